// Round 1
// baseline (189.712 us; speedup 1.0000x reference)
//
#include <hip/hip_runtime.h>
#include <hip/hip_bf16.h>

// ModuleCorefProp2: coref propagation, B=1, K=512, N=16384, D=512, H=64, NB=10, 1 iter.
// Decomposition:
//  prep      : bf16 conversions, Wl|Wr concat, Wg concat, dist table = dist_emb@Wd+bd
//  gemm      : generic 64x64-tile bf16 MFMA GEMM (left/right, p@u, gates)
//  pair      : fused pairwise scorer: per j, prod = u @ (u_j*Wp) via MFMA,
//              epilogue relu/Wo-dot/dist/add_scores -> cs (the 2x8.6 GMAC hot spot)
//  softmax   : masked row softmax (tril / triu structural masks, uniform edge rows)
//  gate etc. : elementwise sigmoid-gates, ss2 = update@Wpr+bpr
//  copy+scatter: all_out assembly

typedef __bf16 bf16;
typedef bf16 bf16x8 __attribute__((ext_vector_type(8)));
typedef float f32x4 __attribute__((ext_vector_type(4)));

#define MFMA16(a, b, c) __builtin_amdgcn_mfma_f32_16x16x32_bf16((a), (b), (c), 0, 0, 0)

// ---------------------------------------------------------------- prep
__global__ void k_prep(const float* __restrict__ sv,
                       const float* __restrict__ Wl, const float* __restrict__ Wr,
                       const float* __restrict__ Wg1, const float* __restrict__ Wg2,
                       const float* __restrict__ de, const float* __restrict__ Wd,
                       const float* __restrict__ bd, const float* __restrict__ bl,
                       const float* __restrict__ br, const float* __restrict__ bg1,
                       const float* __restrict__ bg2,
                       bf16* __restrict__ u1, bf16* __restrict__ ugb,
                       bf16* __restrict__ wlr, float* __restrict__ blbr,
                       float* __restrict__ bgc, bf16* __restrict__ wgb,
                       float* __restrict__ dtab)
{
  const int total = 262144 + 65536 + 128 + 1048576 + 1024 + 640;
  for (int idx0 = blockIdx.x * 256 + threadIdx.x; idx0 < total; idx0 += 2048 * 256) {
    int k = idx0;
    if (k < 262144) {                 // u -> bf16, and left halves of gate inputs
      float v = sv[k]; bf16 b = (bf16)v; u1[k] = b;
      int i = k >> 9, d = k & 511;
      ugb[(long)i * 1024 + d] = b;
      ugb[524288 + (long)i * 1024 + d] = b;
      continue;
    }
    k -= 262144;
    if (k < 65536) {                  // Wlr = [Wl | Wr] bf16 [512][128]
      int d = k >> 7, h = k & 127;
      wlr[k] = (bf16)(h < 64 ? Wl[d * 64 + h] : Wr[d * 64 + h - 64]);
      continue;
    }
    k -= 65536;
    if (k < 128) { blbr[k] = (k < 64 ? bl[k] : br[k - 64]); continue; }
    k -= 128;
    if (k < 1048576) {                // Wg1|Wg2 bf16 [2][1024][512]
      wgb[k] = (bf16)(k < 524288 ? Wg1[k] : Wg2[k - 524288]);
      continue;
    }
    k -= 1048576;
    if (k < 1024) { bgc[k] = (k < 512 ? bg1[k] : bg2[k - 512]); continue; }
    k -= 1024;
    {                                 // dtab[NB][64] = dist_emb@Wd + bd
      int b_ = k >> 6, h = k & 63;
      float s = bd[h];
      for (int e = 0; e < 64; ++e) s += de[b_ * 64 + e] * Wd[e * 64 + h];
      dtab[k] = s;
    }
  }
}

// ---------------------------------------------------------------- generic GEMM
// C[M,N] = A[M,K](bf16) @ B[K,N](bf16) (+bias), 64x64 tiles, 4 waves of 32x32.
__global__ __launch_bounds__(256, 2) void k_gemm(
    const bf16* __restrict__ A, int lda, long asz,
    const bf16* __restrict__ B, int ldb, long bsz,
    float* __restrict__ C, int ldc, long csz,
    const float* __restrict__ bias, int bstride, int K)
{
  __shared__ bf16 As[64 * 40];
  __shared__ bf16 Bs[64 * 40];
  const int t = threadIdx.x, lane = t & 63, wave = t >> 6;
  const int tc = blockIdx.x, tr = blockIdx.y, z = blockIdx.z;
  A += (long)z * asz; B += (long)z * bsz; C += (long)z * csz;
  const int wr = wave >> 1, wc = wave & 1;
  const int arow = t >> 2, aslot = t & 3;
  const int s = lane >> 4, rr = lane & 15;
  f32x4 acc00 = {}, acc01 = {}, acc10 = {}, acc11 = {};
  const int nk = K >> 5;
  for (int kk = 0; kk < nk; ++kk) {
    __syncthreads();
    // stage A tile (64x32)
    *(uint4*)&As[arow * 40 + aslot * 8] =
        *(const uint4*)(A + (long)(tr * 64 + arow) * lda + kk * 32 + aslot * 8);
    // stage B^T tile (64n x 32k)
    {
      const bf16* bsrc = B + (long)(kk * 32 + aslot * 8) * ldb + tc * 64 + arow;
      bf16x8 tv;
#pragma unroll
      for (int e = 0; e < 8; ++e) tv[e] = bsrc[(long)e * ldb];
      *(bf16x8*)&Bs[arow * 40 + aslot * 8] = tv;
    }
    __syncthreads();
    bf16x8 a0 = *(const bf16x8*)&As[(wr * 32 + rr) * 40 + s * 8];
    bf16x8 a1 = *(const bf16x8*)&As[(wr * 32 + 16 + rr) * 40 + s * 8];
    bf16x8 b0 = *(const bf16x8*)&Bs[(wc * 32 + rr) * 40 + s * 8];
    bf16x8 b1 = *(const bf16x8*)&Bs[(wc * 32 + 16 + rr) * 40 + s * 8];
    acc00 = MFMA16(a0, b0, acc00);
    acc01 = MFMA16(a0, b1, acc01);
    acc10 = MFMA16(a1, b0, acc10);
    acc11 = MFMA16(a1, b1, acc11);
  }
  // epilogue
#pragma unroll
  for (int mf = 0; mf < 2; ++mf) {
#pragma unroll
    for (int nf = 0; nf < 2; ++nf) {
      f32x4 v = mf == 0 ? (nf == 0 ? acc00 : acc01) : (nf == 0 ? acc10 : acc11);
      int col = tc * 64 + wc * 32 + nf * 16 + rr;
      float bi = bias ? bias[z * bstride + col] : 0.f;
      int row0 = tr * 64 + wr * 32 + mf * 16 + s * 4;
#pragma unroll
      for (int r = 0; r < 4; ++r)
        C[(long)(row0 + r) * ldc + col] = v[r] + bi;
    }
  }
}

// ---------------------------------------------------------------- fused pair scorer
// Per WG: j0=2*bx, two j's. 8 waves: wave = (wm<<1)|wj, wm in 0..3 (128 i rows), wj in 0..1.
// C[i][h] = sum_d u[i,d] * (u_j[d]*Wp[d,h]); epilogue: cs[i][j].
__global__ __launch_bounds__(512, 1) void k_pair(
    const bf16* __restrict__ Ubf, const float* __restrict__ Uf,
    const float* __restrict__ LR, const float* __restrict__ dtabg,
    const int* __restrict__ sb, const float* __restrict__ ss,
    const float* __restrict__ Wp, const float* __restrict__ Wo,
    const float* __restrict__ bo, float* __restrict__ cs)
{
  __shared__ bf16 Asl[2][512 * 40];   // A slab, rows padded to 40 elems (80B)
  __shared__ bf16 WpT[64 * 520];      // Wp transposed [h][d], rows padded to 520
  __shared__ float ujs[2][512];       // the two u_j rows (f32)
  __shared__ float dts[640];          // dist table [10][64]

  const int t = threadIdx.x;
  const int lane = t & 63;
  const int wave = t >> 6;
  const int wm = wave >> 1, wj = wave & 1;
  const int i0 = wm * 128;
  const int j0 = blockIdx.x * 2;
  const int j = j0 + wj;
  const int arow0 = t >> 2, aslot = t & 3;
  const int s = lane >> 4, rr = lane & 15;

  // issue k-step 0 loads early
  uint4 stg[4];
#pragma unroll
  for (int r = 0; r < 4; ++r) {
    int row = r * 128 + arow0;
    stg[r] = *(const uint4*)(Ubf + row * 512 + aslot * 8);
  }
  // stage u_j rows, WpT, dist table
  for (int idx = t; idx < 1024; idx += 512)
    ujs[idx >> 9][idx & 511] = Uf[(j0 + (idx >> 9)) * 512 + (idx & 511)];
  for (int idx = t; idx < 32768; idx += 512) {
    int d = idx >> 6, h = idx & 63;
    WpT[h * 520 + d] = (bf16)Wp[idx];
  }
  if (t < 640) dts[t] = dtabg[t];
#pragma unroll
  for (int r = 0; r < 4; ++r) {
    int row = r * 128 + arow0;
    *(uint4*)&Asl[0][row * 40 + aslot * 8] = stg[r];
  }
  __syncthreads();

  f32x4 acc[8][4] = {};

  for (int kk = 0; kk < 16; ++kk) {
    const int cur = kk & 1;
    if (kk < 15) {                       // issue next slab loads (hide under MFMA)
#pragma unroll
      for (int r = 0; r < 4; ++r) {
        int row = r * 128 + arow0;
        stg[r] = *(const uint4*)(Ubf + row * 512 + (kk + 1) * 32 + aslot * 8);
      }
    }
    const float* up = &ujs[wj][kk * 32 + s * 8];
    float4 ua = *(const float4*)up;
    float4 ub = *(const float4*)(up + 4);
    bf16x8 af[8];
#pragma unroll
    for (int mf = 0; mf < 8; ++mf)
      af[mf] = *(const bf16x8*)&Asl[cur][(i0 + mf * 16 + rr) * 40 + s * 8];
#pragma unroll
    for (int hf = 0; hf < 4; ++hf) {
      bf16x8 wp8 = *(const bf16x8*)&WpT[(hf * 16 + rr) * 520 + kk * 32 + s * 8];
      bf16x8 bfr;
#pragma unroll
      for (int e = 0; e < 4; ++e) {
        bfr[e] = (bf16)(ua[e] * (float)wp8[e]);
        bfr[e + 4] = (bf16)(ub[e] * (float)wp8[e + 4]);
      }
#pragma unroll
      for (int mf = 0; mf < 8; ++mf)
        acc[mf][hf] = MFMA16(af[mf], bfr, acc[mf][hf]);
    }
    if (kk < 15) {                       // commit next slab after compute
#pragma unroll
      for (int r = 0; r < 4; ++r) {
        int row = r * 128 + arow0;
        *(uint4*)&Asl[cur ^ 1][row * 40 + aslot * 8] = stg[r];
      }
    }
    __syncthreads();
  }

  // epilogue: cs[i][j] = (i==j) ? 0 : sum_h Wo[h]*relu(prod+left+right+dist) + bo + ss[i] + ss[j]
  float wo4[4], rj4[4];
#pragma unroll
  for (int hf = 0; hf < 4; ++hf) {
    wo4[hf] = Wo[hf * 16 + rr];
    rj4[hf] = LR[j * 128 + 64 + hf * 16 + rr];
  }
  const int sbj = sb[j];
  const float ssj = ss[j];
  const float bo0 = bo[0];
#pragma unroll
  for (int mf = 0; mf < 8; ++mf) {
#pragma unroll
    for (int r = 0; r < 4; ++r) {
      int i = i0 + mf * 16 + s * 4 + r;
      int dd = sb[i] - sbj;
      int ad = dd < 0 ? -dd : dd;
      int bkt = ad < 5 ? ad : (31 - __clz(ad)) + 3;
      bkt = bkt > 9 ? 9 : bkt;
      float sum = 0.f;
#pragma unroll
      for (int hf = 0; hf < 4; ++hf) {
        float v = acc[mf][hf][r] + LR[i * 128 + hf * 16 + rr] + rj4[hf] +
                  dts[bkt * 64 + hf * 16 + rr];
        v = fmaxf(v, 0.f);
        sum += v * wo4[hf];
      }
      sum += __shfl_xor(sum, 1);
      sum += __shfl_xor(sum, 2);
      sum += __shfl_xor(sum, 4);
      sum += __shfl_xor(sum, 8);
      if (rr == 0) {
        float val = (i == j) ? 0.f : (sum + bo0 + ss[i] + ssj);
        cs[i * 512 + j] = val;
      }
    }
  }
}

// ---------------------------------------------------------------- masked softmax rows
// block b<512: p1 row (mask j<i); b>=512: p2 row (mask j>i). All-masked -> uniform 1/512.
__global__ __launch_bounds__(64) void k_softmax(const float* __restrict__ cs,
                                                bf16* __restrict__ p12)
{
  int b = blockIdx.x, kind = b >> 9, i = b & 511, lane = threadIdx.x;
  const float* row = cs + i * 512;
  float v[8];
  float4 x0 = *(const float4*)(row + lane * 8);
  float4 x1 = *(const float4*)(row + lane * 8 + 4);
  v[0] = x0.x; v[1] = x0.y; v[2] = x0.z; v[3] = x0.w;
  v[4] = x1.x; v[5] = x1.y; v[6] = x1.z; v[7] = x1.w;
  bool any = (kind == 0) ? (i > 0) : (i < 511);
  bf16x8 ov;
  if (!any) {
    float u = 1.0f / 512.0f;
#pragma unroll
    for (int e = 0; e < 8; ++e) ov[e] = (bf16)u;
  } else {
    float m = -3.4e38f;
#pragma unroll
    for (int e = 0; e < 8; ++e) {
      int jj = lane * 8 + e;
      bool valid = (kind == 0) ? (jj < i) : (jj > i);
      if (valid) m = fmaxf(m, v[e]);
    }
    m = fmaxf(m, __shfl_xor(m, 1));  m = fmaxf(m, __shfl_xor(m, 2));
    m = fmaxf(m, __shfl_xor(m, 4));  m = fmaxf(m, __shfl_xor(m, 8));
    m = fmaxf(m, __shfl_xor(m, 16)); m = fmaxf(m, __shfl_xor(m, 32));
    float p[8]; float ssum = 0.f;
#pragma unroll
    for (int e = 0; e < 8; ++e) {
      int jj = lane * 8 + e;
      bool valid = (kind == 0) ? (jj < i) : (jj > i);
      p[e] = valid ? __expf(v[e] - m) : 0.f;
      ssum += p[e];
    }
    ssum += __shfl_xor(ssum, 1);  ssum += __shfl_xor(ssum, 2);
    ssum += __shfl_xor(ssum, 4);  ssum += __shfl_xor(ssum, 8);
    ssum += __shfl_xor(ssum, 16); ssum += __shfl_xor(ssum, 32);
    float inv = 1.0f / ssum;
#pragma unroll
    for (int e = 0; e < 8; ++e) ov[e] = (bf16)(p[e] * inv);
  }
  *(bf16x8*)(p12 + (long)b * 512 + lane * 8) = ov;
}

// ---------------------------------------------------------------- gate input build
__global__ void k_gatein(const float* __restrict__ c12, bf16* __restrict__ ugb)
{
  for (int idx = blockIdx.x * 256 + threadIdx.x; idx < 262144; idx += 512 * 256) {
    int i = idx >> 9, d = idx & 511;
    ugb[(long)i * 1024 + 512 + d] = (bf16)c12[idx];
    ugb[524288 + (long)i * 1024 + 512 + d] = (bf16)c12[262144 + idx];
  }
}

// ---------------------------------------------------------------- gates + update
__global__ void k_gate(const float* __restrict__ sv, const float* __restrict__ c12,
                       const float* __restrict__ G12, float* __restrict__ upd,
                       bf16* __restrict__ u2)
{
  for (int idx = blockIdx.x * 256 + threadIdx.x; idx < 262144; idx += 512 * 256) {
    float u = sv[idx], c1 = c12[idx], c2 = c12[262144 + idx];
    float g1 = 1.f / (1.f + __expf(-G12[idx]));
    float g2 = 1.f / (1.f + __expf(-G12[262144 + idx]));
    float up = g1 * u + (1.f - g1) * c1 + g2 * u + (1.f - g2) * c2;
    upd[idx] = up;
    u2[idx] = (bf16)up;
  }
}

// ---------------------------------------------------------------- ss2 = update@Wpr + bpr
__global__ __launch_bounds__(64) void k_ss2(const float* __restrict__ upd,
                                            const float* __restrict__ Wpr,
                                            const float* __restrict__ bpr,
                                            float* __restrict__ ss2)
{
  int row = blockIdx.x, lane = threadIdx.x;
  const float* rp = upd + row * 512 + lane * 8;
  const float* wp = Wpr + lane * 8;
  float4 a0 = *(const float4*)rp, a1 = *(const float4*)(rp + 4);
  float4 b0 = *(const float4*)wp, b1 = *(const float4*)(wp + 4);
  float s = a0.x * b0.x + a0.y * b0.y + a0.z * b0.z + a0.w * b0.w +
            a1.x * b1.x + a1.y * b1.y + a1.z * b1.z + a1.w * b1.w;
  s += __shfl_xor(s, 1);  s += __shfl_xor(s, 2);  s += __shfl_xor(s, 4);
  s += __shfl_xor(s, 8);  s += __shfl_xor(s, 16); s += __shfl_xor(s, 32);
  if (lane == 0) ss2[row] = s + bpr[0];
}

// ---------------------------------------------------------------- all_out assembly
__global__ void k_copy(const float* __restrict__ in, float* __restrict__ out)
{
  const float4* i4 = (const float4*)in;
  float4* o4 = (float4*)out;
  for (int idx = blockIdx.x * 256 + threadIdx.x; idx < 2097152; idx += 2048 * 256)
    o4[idx] = i4[idx];
}

__global__ __launch_bounds__(64) void k_scatter(const float* __restrict__ upd,
                                                const int* __restrict__ pi,
                                                const int* __restrict__ sl,
                                                float* __restrict__ out)
{
  int k = blockIdx.x;
  if (k >= sl[0]) return;
  int dst = pi[k];
  int lane = threadIdx.x;
  const float4* s4 = (const float4*)(upd + k * 512);
  float4* d4 = (float4*)(out + (long)dst * 512);
  d4[lane * 2] = s4[lane * 2];
  d4[lane * 2 + 1] = s4[lane * 2 + 1];
}

// ---------------------------------------------------------------- launch
extern "C" void kernel_launch(void* const* d_in, const int* in_sizes, int n_in,
                              void* d_out, int out_size, void* d_ws, size_t ws_size,
                              hipStream_t stream)
{
  const float* asv = (const float*)d_in[0];
  const float* sv = (const float*)d_in[1];
  const int* sb = (const int*)d_in[2];
  const float* sscore = (const float*)d_in[5];
  const int* pi = (const int*)d_in[6];
  const int* sl = (const int*)d_in[7];
  const float* Wl = (const float*)d_in[9];
  const float* bl = (const float*)d_in[10];
  const float* Wr = (const float*)d_in[11];
  const float* br = (const float*)d_in[12];
  const float* Wp = (const float*)d_in[13];
  const float* de = (const float*)d_in[14];
  const float* Wd = (const float*)d_in[15];
  const float* bd = (const float*)d_in[16];
  const float* Wo = (const float*)d_in[17];
  const float* bo = (const float*)d_in[18];
  const float* Wg1 = (const float*)d_in[19];
  const float* bg1 = (const float*)d_in[20];
  const float* Wg2 = (const float*)d_in[21];
  const float* bg2 = (const float*)d_in[22];
  const float* Wpr = (const float*)d_in[23];
  const float* bpr = (const float*)d_in[24];

  float* out_all = (float*)d_out;
  float* out_upd = out_all + 8388608;   // [512][512] update
  float* out_cs = out_all + 8650752;    // [512][512] cs

  char* w = (char*)d_ws;
  size_t off = 0;
  auto take = [&](size_t bytes) -> void* {
    void* p = w + off;
    off = (off + bytes + 255) & ~(size_t)255;
    return p;
  };
  bf16* u1b = (bf16*)take(524288);
  bf16* u2b = (bf16*)take(524288);
  bf16* wlr = (bf16*)take(131072);
  bf16* wgb = (bf16*)take(2097152);
  float* blbr = (float*)take(512);
  float* bgc = (float*)take(4096);
  float* dtab = (float*)take(2560);
  float* lr1 = (float*)take(262144);
  float* lr2 = (float*)take(262144);
  float* cs1 = (float*)take(1048576);
  bf16* p12 = (bf16*)take(1048576);
  float* c12 = (float*)take(4194304);
  bf16* ugb = (bf16*)take(2097152);
  float* G12 = (float*)take(2097152);
  float* ss2 = (float*)take(2048);

  k_prep<<<2048, 256, 0, stream>>>(sv, Wl, Wr, Wg1, Wg2, de, Wd, bd, bl, br, bg1, bg2,
                                   u1b, ugb, wlr, blbr, bgc, wgb, dtab);
  // left|right for u
  k_gemm<<<dim3(2, 8, 1), 256, 0, stream>>>(u1b, 512, 0, wlr, 128, 0, lr1, 128, 0,
                                            blbr, 0, 512);
  // cs1 = add_scores(pair_scores(u), span_scores)
  k_pair<<<256, 512, 0, stream>>>(u1b, sv, lr1, dtab, sb, sscore, Wp, Wo, bo, cs1);
  // p1,p2
  k_softmax<<<1024, 64, 0, stream>>>(cs1, p12);
  // c1,c2 = [p1;p2] @ u
  k_gemm<<<dim3(8, 16, 1), 256, 0, stream>>>(p12, 512, 0, u1b, 512, 0, c12, 512, 0,
                                             nullptr, 0, 512);
  k_gatein<<<512, 256, 0, stream>>>(c12, ugb);
  // G1,G2 = [u|c] @ Wg + bg   (batched z=2, K=1024)
  k_gemm<<<dim3(8, 8, 2), 256, 0, stream>>>(ugb, 1024, 524288, wgb, 512, 524288,
                                            G12, 512, 262144, bgc, 512, 1024);
  k_gate<<<512, 256, 0, stream>>>(sv, c12, G12, out_upd, u2b);
  k_ss2<<<512, 64, 0, stream>>>(out_upd, Wpr, bpr, ss2);
  // left|right for update
  k_gemm<<<dim3(2, 8, 1), 256, 0, stream>>>(u2b, 512, 0, wlr, 128, 0, lr2, 128, 0,
                                            blbr, 0, 512);
  // cs = add_scores(pair_scores(update), update@Wpr+bpr)
  k_pair<<<256, 512, 0, stream>>>(u2b, out_upd, lr2, dtab, sb, ss2, Wp, Wo, bo, out_cs);
  // all_out
  k_copy<<<2048, 256, 0, stream>>>(asv, out_all);
  k_scatter<<<512, 64, 0, stream>>>(out_upd, pi, sl, out_all);
}